// Round 5
// baseline (1206.329 us; speedup 1.0000x reference)
//
#include <hip/hip_runtime.h>
#include <hip/hip_bf16.h>
#include <math.h>

#define NFEAT 128
#define NCLASS 40

// ---------------- CSR build ----------------

__global__ __launch_bounds__(256) void hist_kernel(const int* __restrict__ dst,
                                                   int* __restrict__ counts, int n_edges) {
    int e = blockIdx.x * 256 + threadIdx.x;
    if (e < n_edges) atomicAdd(&counts[dst[e]], 1);
}

__global__ __launch_bounds__(256) void scan1_kernel(const int* __restrict__ cnt,
                                                    int* __restrict__ excl,
                                                    int* __restrict__ bsums, int n) {
    __shared__ int sd[256];
    int t = threadIdx.x;
    int i = blockIdx.x * 256 + t;
    int v = (i < n) ? cnt[i] : 0;
    sd[t] = v;
    __syncthreads();
#pragma unroll
    for (int off = 1; off < 256; off <<= 1) {
        int tmp = (t >= off) ? sd[t - off] : 0;
        __syncthreads();
        sd[t] += tmp;
        __syncthreads();
    }
    if (i < n) excl[i] = sd[t] - v;
    if (t == 255) bsums[blockIdx.x] = sd[255];
}

__global__ __launch_bounds__(256) void scan2_kernel(int* __restrict__ bsums, int nb) {
    __shared__ int sd[256];
    int t = threadIdx.x;
    int v = (t < nb) ? bsums[t] : 0;
    sd[t] = v;
    __syncthreads();
#pragma unroll
    for (int off = 1; off < 256; off <<= 1) {
        int tmp = (t >= off) ? sd[t - off] : 0;
        __syncthreads();
        sd[t] += tmp;
        __syncthreads();
    }
    if (t < nb) bsums[t] = sd[t] - v;
    if (t == 255) bsums[nb] = sd[255];
}

__global__ __launch_bounds__(256) void scan3_kernel(const int* __restrict__ excl,
                                                    const int* __restrict__ bsums,
                                                    int* __restrict__ row_ptr,
                                                    int* __restrict__ woff, int n, int nb) {
    int i = blockIdx.x * 256 + threadIdx.x;
    if (i < n) {
        int v = excl[i] + bsums[blockIdx.x];
        row_ptr[i] = v;
        woff[i] = v;
    }
    if (i == 0) row_ptr[n] = bsums[nb];
}

__global__ __launch_bounds__(256) void scatter_kernel(const int* __restrict__ src,
                                                      const int* __restrict__ dst,
                                                      int* __restrict__ woff,
                                                      int* __restrict__ src_sorted, int n_edges) {
    int e = blockIdx.x * 256 + threadIdx.x;
    if (e < n_edges) {
        int p = atomicAdd(&woff[dst[e]], 1);
        src_sorted[p] = src[e];
    }
}

// ---------------- fused layer via ticketed producer/consumer blocks ----------------
// Grid = 2*NT blocks. Atomic ticket: tickets [0,NT) gather tile t (64 nodes)
// into global agg (high-occupancy, LDS-free, the proven 3.6 TB/s shape);
// tickets [NT,2NT) run the VALU-bound gemm+bias+norm+relu on tile t-NT,
// gated by a device-scope flag (threadfence + atomic). Ticket grab order ==
// temporal order, so the gather for any gemm ticket is resident-or-done:
// no deadlock regardless of dispatch order. Gather (memory pipe) and gemm
// (VALU pipe) overlap across blocks on each CU.

__global__ __launch_bounds__(256) void layer_kernel(const float* __restrict__ xin,
                                                    const int* __restrict__ row_ptr,
                                                    const int* __restrict__ src_sorted,
                                                    const float* __restrict__ W,
                                                    const float* __restrict__ bias,
                                                    float* __restrict__ agg,
                                                    float* __restrict__ out, int M, int NT,
                                                    int* __restrict__ flags,
                                                    int* __restrict__ ticket) {
    __shared__ int tkt_s;
    __shared__ float ss_lds[4][64];
    if (threadIdx.x == 0) tkt_s = atomicAdd(ticket, 1);
    __syncthreads();
    int t = tkt_s;

    if (t < NT) {
        // ---- producer: gather tile t ----
        int base = t * 64;
        int hw = threadIdx.x >> 5;  // half-wave 0..7
        int c = threadIdx.x & 31;   // float4 column group
        const float4* xp = (const float4*)xin;
#pragma unroll
        for (int i = 0; i < 8; ++i) {
            int node = base + hw * 8 + i;
            int nc = node < M ? node : M - 1;
            int jb = row_ptr[nc], je = row_ptr[nc + 1];
            if (node >= M) je = jb;
            float4 a0 = make_float4(0.f, 0.f, 0.f, 0.f);
            float4 a1 = make_float4(0.f, 0.f, 0.f, 0.f);
            float4 a2 = make_float4(0.f, 0.f, 0.f, 0.f);
            float4 a3 = make_float4(0.f, 0.f, 0.f, 0.f);
            int j = jb;
            for (; j + 3 < je; j += 4) {
                int s0 = src_sorted[j];
                int s1 = src_sorted[j + 1];
                int s2 = src_sorted[j + 2];
                int s3 = src_sorted[j + 3];
                float4 v0 = xp[s0 * 32 + c];
                float4 v1 = xp[s1 * 32 + c];
                float4 v2 = xp[s2 * 32 + c];
                float4 v3 = xp[s3 * 32 + c];
                a0.x += v0.x; a0.y += v0.y; a0.z += v0.z; a0.w += v0.w;
                a1.x += v1.x; a1.y += v1.y; a1.z += v1.z; a1.w += v1.w;
                a2.x += v2.x; a2.y += v2.y; a2.z += v2.z; a2.w += v2.w;
                a3.x += v3.x; a3.y += v3.y; a3.z += v3.z; a3.w += v3.w;
            }
            for (; j < je; ++j) {
                int s0 = src_sorted[j];
                float4 v0 = xp[s0 * 32 + c];
                a0.x += v0.x; a0.y += v0.y; a0.z += v0.z; a0.w += v0.w;
            }
            a0.x += a1.x + a2.x + a3.x;
            a0.y += a1.y + a2.y + a3.y;
            a0.z += a1.z + a2.z + a3.z;
            a0.w += a1.w + a2.w + a3.w;
            if (node < M) ((float4*)agg)[node * 32 + c] = a0;
        }
        __syncthreads();
        __threadfence();  // device-scope: publish agg before flag (G16)
        if (threadIdx.x == 0) atomicExch(&flags[t], 1);
    } else {
        // ---- consumer: gemm tile u ----
        int u = t - NT;
        if (threadIdx.x == 0) {
            while (atomicAdd(&flags[u], 0) == 0) __builtin_amdgcn_s_sleep(8);
        }
        __syncthreads();
        __threadfence();  // acquire side

        int lane = threadIdx.x & 63;
        int wv = threadIdx.x >> 6;
        int c0 = __builtin_amdgcn_readfirstlane(wv * 32);  // wave-uniform col base
        int node = u * 64 + lane;
        int nclamp = node < M ? node : M - 1;
        const float* Arow = agg + (size_t)nclamp * NFEAT;

        float acc[32];
#pragma unroll
        for (int i = 0; i < 32; ++i) acc[i] = 0.f;

        for (int k = 0; k < NFEAT; k += 4) {
            float4 a = *(const float4*)(Arow + k);
#pragma unroll
            for (int kk = 0; kk < 4; ++kk) {
                float av = (&a.x)[kk];
                const float* Wr = W + (k + kk) * NFEAT + c0;  // uniform -> s_load
#pragma unroll
                for (int c = 0; c < 32; ++c) acc[c] += av * Wr[c];
            }
        }

        float ss = 0.f;
#pragma unroll
        for (int c = 0; c < 32; ++c) {
            acc[c] += bias[c0 + c];
            ss += acc[c] * acc[c];
        }
        ss_lds[wv][lane] = ss;
        __syncthreads();
        float tot = ss_lds[0][lane] + ss_lds[1][lane] + ss_lds[2][lane] + ss_lds[3][lane];
        float inv = 1.0f / fmaxf(sqrtf(tot), 1e-12f);

        if (node < M) {
            float4* o = (float4*)(out + (size_t)node * NFEAT + c0);
#pragma unroll
            for (int c = 0; c < 32; c += 4) {
                float4 v;
                v.x = fmaxf(acc[c + 0] * inv, 0.f);
                v.y = fmaxf(acc[c + 1] * inv, 0.f);
                v.z = fmaxf(acc[c + 2] * inv, 0.f);
                v.w = fmaxf(acc[c + 3] * inv, 0.f);
                o[c >> 2] = v;
            }
        }
    }
}

// ---------------- classifier: logits = x4 @ Wl + bl; softmax ----------------

__global__ __launch_bounds__(256) void classifier_kernel(const float* __restrict__ x4,
                                                         const float* __restrict__ Wl,
                                                         const float* __restrict__ bl,
                                                         float* __restrict__ logits,
                                                         float* __restrict__ probs, int n_nodes) {
    int node = blockIdx.x * 256 + threadIdx.x;
    int nc = node < n_nodes ? node : n_nodes - 1;
    const float* row = x4 + (size_t)nc * NFEAT;

    float acc[NCLASS];
#pragma unroll
    for (int c = 0; c < NCLASS; ++c) acc[c] = bl[c];  // uniform -> s_load

    for (int k = 0; k < NFEAT; k += 4) {
        float4 a = *(const float4*)(row + k);
#pragma unroll
        for (int kk = 0; kk < 4; ++kk) {
            float av = (&a.x)[kk];
            const float* Wr = Wl + (k + kk) * NCLASS;  // uniform address
#pragma unroll
            for (int c = 0; c < NCLASS; ++c) acc[c] += av * Wr[c];
        }
    }

    float m = acc[0];
#pragma unroll
    for (int c = 1; c < NCLASS; ++c) m = fmaxf(m, acc[c]);
    float ex[NCLASS];
    float sum = 0.f;
#pragma unroll
    for (int c = 0; c < NCLASS; ++c) {
        ex[c] = __expf(acc[c] - m);
        sum += ex[c];
    }
    float is = 1.0f / sum;

    if (node < n_nodes) {
        float4* lo = (float4*)(logits + (size_t)node * NCLASS);
        float4* po = (float4*)(probs + (size_t)node * NCLASS);
#pragma unroll
        for (int c = 0; c < NCLASS; c += 4) {
            float4 lv, pv;
            lv.x = acc[c + 0]; lv.y = acc[c + 1]; lv.z = acc[c + 2]; lv.w = acc[c + 3];
            pv.x = ex[c + 0] * is; pv.y = ex[c + 1] * is; pv.z = ex[c + 2] * is; pv.w = ex[c + 3] * is;
            lo[c >> 2] = lv;
            po[c >> 2] = pv;
        }
    }
}

// ---------------- launch ----------------

extern "C" void kernel_launch(void* const* d_in, const int* in_sizes, int n_in,
                              void* d_out, int out_size, void* d_ws, size_t ws_size,
                              hipStream_t stream) {
    const float* x  = (const float*)d_in[0];
    const int*   ei = (const int*)d_in[1];
    const float* W1 = (const float*)d_in[2];
    const float* b1 = (const float*)d_in[3];
    const float* W2 = (const float*)d_in[4];
    const float* b2 = (const float*)d_in[5];
    const float* W3 = (const float*)d_in[6];
    const float* b3 = (const float*)d_in[7];
    const float* W4 = (const float*)d_in[8];
    const float* b4 = (const float*)d_in[9];
    const float* Wl = (const float*)d_in[10];
    const float* bl = (const float*)d_in[11];

    const int n_nodes = in_sizes[0] / NFEAT;  // 50000
    const int n_edges = in_sizes[1] / 2;      // 640000
    const int* src = ei;
    const int* dst = ei + n_edges;

    float* out    = (float*)d_out;
    float* logits = out;
    float* probs  = out + (size_t)n_nodes * NCLASS;
    float* x4     = out + 2 * (size_t)n_nodes * NCLASS;  // layer ping buffer

    // workspace layout
    char* ws = (char*)d_ws;
    size_t off = 0;
    auto wsalloc = [&](size_t bytes) -> void* {
        void* p = ws + off;
        off += (bytes + 255) & ~(size_t)255;
        return p;
    };
    float* agg        = (float*)wsalloc((size_t)n_nodes * NFEAT * sizeof(float));
    float* xbuf       = (float*)wsalloc((size_t)n_nodes * NFEAT * sizeof(float));  // layer pong
    int*   row_ptr    = (int*)wsalloc(((size_t)n_nodes + 1) * sizeof(int));
    int*   woff       = (int*)wsalloc((size_t)n_nodes * sizeof(int));
    int*   cnt        = (int*)wsalloc((size_t)n_nodes * sizeof(int));
    int*   src_sorted = (int*)wsalloc((size_t)n_edges * sizeof(int));
    int    nb         = (n_nodes + 255) / 256;
    int*   bsums      = (int*)wsalloc(((size_t)nb + 1) * sizeof(int));
    int    NT         = (n_nodes + 63) / 64;  // 782 tiles
    int*   flagbuf    = (int*)wsalloc(((size_t)4 * 1024 + 4) * sizeof(int));  // flags[4][1024] + tickets[4]

    // zero counters/flags/tickets (in-stream, graph-capture safe)
    hipMemsetAsync(cnt, 0, (size_t)n_nodes * sizeof(int), stream);
    hipMemsetAsync(flagbuf, 0, ((size_t)4 * 1024 + 4) * sizeof(int), stream);

    // CSR build (dst-bucketed)
    int eb = (n_edges + 255) / 256;
    hist_kernel<<<eb, 256, 0, stream>>>(dst, cnt, n_edges);
    scan1_kernel<<<nb, 256, 0, stream>>>(cnt, row_ptr /*excl temp*/, bsums, n_nodes);
    scan2_kernel<<<1, 256, 0, stream>>>(bsums, nb);
    scan3_kernel<<<nb, 256, 0, stream>>>(row_ptr, bsums, row_ptr, woff, n_nodes, nb);
    scatter_kernel<<<eb, 256, 0, stream>>>(src, dst, woff, src_sorted, n_edges);

    int lg = 2 * NT;
    int cb = (n_nodes + 255) / 256;

    // fused layers (agg-first reordering: segment_sum commutes with @W)
    layer_kernel<<<lg, 256, 0, stream>>>(x,    row_ptr, src_sorted, W1, b1, agg, xbuf, n_nodes, NT,
                                         flagbuf + 0 * 1024, flagbuf + 4096 + 0);
    layer_kernel<<<lg, 256, 0, stream>>>(xbuf, row_ptr, src_sorted, W2, b2, agg, x4,   n_nodes, NT,
                                         flagbuf + 1 * 1024, flagbuf + 4096 + 1);
    layer_kernel<<<lg, 256, 0, stream>>>(x4,   row_ptr, src_sorted, W3, b3, agg, xbuf, n_nodes, NT,
                                         flagbuf + 2 * 1024, flagbuf + 4096 + 2);
    layer_kernel<<<lg, 256, 0, stream>>>(xbuf, row_ptr, src_sorted, W4, b4, agg, x4,   n_nodes, NT,
                                         flagbuf + 3 * 1024, flagbuf + 4096 + 3);

    // classifier + softmax
    classifier_kernel<<<cb, 256, 0, stream>>>(x4, Wl, bl, logits, probs, n_nodes);
}

// Round 6
// 453.588 us; speedup vs baseline: 2.6595x; 2.6595x over previous
//
#include <hip/hip_runtime.h>
#include <hip/hip_bf16.h>
#include <math.h>

#define NFEAT 128
#define NCLASS 40

typedef __attribute__((ext_vector_type(8))) short frag_ab;   // 8 bf16 (4 VGPRs)
typedef __attribute__((ext_vector_type(4))) float frag_cd;   // 4 fp32 acc

static __device__ inline unsigned short f2bf_rne(float f) {
    union { float f; unsigned u; } v;
    v.f = f;
    unsigned r = v.u + 0x7FFFu + ((v.u >> 16) & 1u);  // round-to-nearest-even
    return (unsigned short)(r >> 16);
}
static __device__ inline float bf2f(unsigned short h) {
    union { unsigned u; float f; } v;
    v.u = ((unsigned)h) << 16;
    return v.f;
}

// ---------------- CSR build ----------------

__global__ __launch_bounds__(256) void hist_kernel(const int* __restrict__ dst,
                                                   int* __restrict__ counts, int n_edges) {
    int e = blockIdx.x * 256 + threadIdx.x;
    if (e < n_edges) atomicAdd(&counts[dst[e]], 1);
}

__global__ __launch_bounds__(256) void scan1_kernel(const int* __restrict__ cnt,
                                                    int* __restrict__ excl,
                                                    int* __restrict__ bsums, int n) {
    __shared__ int sd[256];
    int t = threadIdx.x;
    int i = blockIdx.x * 256 + t;
    int v = (i < n) ? cnt[i] : 0;
    sd[t] = v;
    __syncthreads();
#pragma unroll
    for (int off = 1; off < 256; off <<= 1) {
        int tmp = (t >= off) ? sd[t - off] : 0;
        __syncthreads();
        sd[t] += tmp;
        __syncthreads();
    }
    if (i < n) excl[i] = sd[t] - v;
    if (t == 255) bsums[blockIdx.x] = sd[255];
}

__global__ __launch_bounds__(256) void scan2_kernel(int* __restrict__ bsums, int nb) {
    __shared__ int sd[256];
    int t = threadIdx.x;
    int v = (t < nb) ? bsums[t] : 0;
    sd[t] = v;
    __syncthreads();
#pragma unroll
    for (int off = 1; off < 256; off <<= 1) {
        int tmp = (t >= off) ? sd[t - off] : 0;
        __syncthreads();
        sd[t] += tmp;
        __syncthreads();
    }
    if (t < nb) bsums[t] = sd[t] - v;
    if (t == 255) bsums[nb] = sd[255];
}

__global__ __launch_bounds__(256) void scan3_kernel(const int* __restrict__ excl,
                                                    const int* __restrict__ bsums,
                                                    int* __restrict__ row_ptr,
                                                    int* __restrict__ woff, int n, int nb) {
    int i = blockIdx.x * 256 + threadIdx.x;
    if (i < n) {
        int v = excl[i] + bsums[blockIdx.x];
        row_ptr[i] = v;
        woff[i] = v;
    }
    if (i == 0) row_ptr[n] = bsums[nb];
}

__global__ __launch_bounds__(256) void scatter_kernel(const int* __restrict__ src,
                                                      const int* __restrict__ dst,
                                                      int* __restrict__ woff,
                                                      int* __restrict__ src_sorted, int n_edges) {
    int e = blockIdx.x * 256 + threadIdx.x;
    if (e < n_edges) {
        int p = atomicAdd(&woff[dst[e]], 1);
        src_sorted[p] = src[e];
    }
}

// ---------------- aggregation (R2 proven shape: 46.5 us, 3.6 TB/s) ----------------
// Half-wave (32 lanes x float4 = full 128-col row) per node; 4-deep gather pipeline.

__global__ __launch_bounds__(256) void agg_kernel(const float* __restrict__ xin,
                                                  const int* __restrict__ row_ptr,
                                                  const int* __restrict__ src_sorted,
                                                  float* __restrict__ agg, int n_nodes) {
    int node = blockIdx.x * 8 + (threadIdx.x >> 5);
    if (node >= n_nodes) return;
    int c = threadIdx.x & 31;
    int jb = row_ptr[node], je = row_ptr[node + 1];
    const float4* xp = (const float4*)xin;

    float4 a0 = make_float4(0.f, 0.f, 0.f, 0.f);
    float4 a1 = make_float4(0.f, 0.f, 0.f, 0.f);
    float4 a2 = make_float4(0.f, 0.f, 0.f, 0.f);
    float4 a3 = make_float4(0.f, 0.f, 0.f, 0.f);
    int j = jb;
    for (; j + 3 < je; j += 4) {
        int s0 = src_sorted[j];
        int s1 = src_sorted[j + 1];
        int s2 = src_sorted[j + 2];
        int s3 = src_sorted[j + 3];
        float4 v0 = xp[s0 * 32 + c];
        float4 v1 = xp[s1 * 32 + c];
        float4 v2 = xp[s2 * 32 + c];
        float4 v3 = xp[s3 * 32 + c];
        a0.x += v0.x; a0.y += v0.y; a0.z += v0.z; a0.w += v0.w;
        a1.x += v1.x; a1.y += v1.y; a1.z += v1.z; a1.w += v1.w;
        a2.x += v2.x; a2.y += v2.y; a2.z += v2.z; a2.w += v2.w;
        a3.x += v3.x; a3.y += v3.y; a3.z += v3.z; a3.w += v3.w;
    }
    for (; j < je; ++j) {
        int s0 = src_sorted[j];
        float4 v0 = xp[s0 * 32 + c];
        a0.x += v0.x; a0.y += v0.y; a0.z += v0.z; a0.w += v0.w;
    }
    a0.x += a1.x + a2.x + a3.x;
    a0.y += a1.y + a2.y + a3.y;
    a0.z += a1.z + a2.z + a3.z;
    a0.w += a1.w + a2.w + a3.w;
    ((float4*)agg)[node * 32 + c] = a0;
}

// ---------------- W fragment prep: swizzle all 4 layer weights into MFMA B-frag layout ----------------
// B-frag for mfma_f32_16x16x32_bf16: lane holds B[k = quad*8+j][n = lane&15], j=0..7.
// Frag slot f = (s*8 + t)*64 + lane  (s = k-step 0..3, t = 16-col tile 0..7).
// hi = bf16(w), lo = bf16(w - hi): split-fp32 for ~fp32 accuracy via 3 MFMAs.

__global__ __launch_bounds__(256) void wprep_kernel(const float* __restrict__ W0,
                                                    const float* __restrict__ W1,
                                                    const float* __restrict__ W2,
                                                    const float* __restrict__ W3,
                                                    short* __restrict__ whi,
                                                    short* __restrict__ wlo) {
    int layer = blockIdx.y;
    const float* W = layer == 0 ? W0 : layer == 1 ? W1 : layer == 2 ? W2 : W3;
    short* h = whi + (size_t)layer * 16384;
    short* l = wlo + (size_t)layer * 16384;
    int idx = blockIdx.x * 256 + threadIdx.x;  // 0..2047 frag slots
    int lane = idx & 63;
    int t = (idx >> 6) & 7;
    int s = idx >> 9;
    int quad = lane >> 4;
    int n = lane & 15;
    int kbase = s * 32 + quad * 8;
    int col = t * 16 + n;
#pragma unroll
    for (int j = 0; j < 8; ++j) {
        float f = W[(size_t)(kbase + j) * NFEAT + col];
        unsigned short hb = f2bf_rne(f);
        unsigned short lb = f2bf_rne(f - bf2f(hb));
        h[(size_t)idx * 8 + j] = (short)hb;
        l[(size_t)idx * 8 + j] = (short)lb;
    }
}

// ---------------- MFMA GEMM (M x 128 @ 128 x 128) + bias + L2-normalize + ReLU ----------------
// Block = 64 rows, 4 waves; wave w owns rows [base+16w, base+16w+16) x all 128 cols
// (8 tiles of 16). Split-bf16: acc = hi*hi + hi*lo + lo*hi (fp32 accumulate).
// A-frag layout: A[m=lane&15][k=quad*8+j] -> 2 coalesced float4 loads per k-step.
// C/D layout: col=lane&15, row=quad*4+reg (guide-verified). Row-norm: in-register
// tile sum + shfl_xor over the 16 lanes of the quad (cols 0..15 of each tile).

__global__ __launch_bounds__(256) void gemm_mfma_kernel(const float* __restrict__ A,
                                                        const short* __restrict__ whi,
                                                        const short* __restrict__ wlo,
                                                        const float* __restrict__ bias,
                                                        float* __restrict__ out, int M) {
    int tid = threadIdx.x;
    int wave = tid >> 6;
    int lane = tid & 63;
    int quad = lane >> 4;
    int n16 = lane & 15;
    int base = blockIdx.x * 64;

    int arow = base + wave * 16 + n16;
    int arc = arow < M ? arow : M - 1;
    const float* Ar = A + (size_t)arc * NFEAT;

    const frag_ab* WH = (const frag_ab*)whi;
    const frag_ab* WL = (const frag_ab*)wlo;

    frag_cd acc[8];
#pragma unroll
    for (int t = 0; t < 8; ++t) acc[t] = (frag_cd){0.f, 0.f, 0.f, 0.f};

#pragma unroll
    for (int s = 0; s < 4; ++s) {
        const float* ap = Ar + s * 32 + quad * 8;
        float4 x0 = *(const float4*)ap;
        float4 x1 = *(const float4*)(ap + 4);
        float xs[8] = {x0.x, x0.y, x0.z, x0.w, x1.x, x1.y, x1.z, x1.w};
        frag_ab ah, al;
#pragma unroll
        for (int j = 0; j < 8; ++j) {
            unsigned short hb = f2bf_rne(xs[j]);
            ah[j] = (short)hb;
            al[j] = (short)f2bf_rne(xs[j] - bf2f(hb));
        }
#pragma unroll
        for (int t = 0; t < 8; ++t) {
            frag_ab bh = WH[(s * 8 + t) * 64 + lane];
            frag_ab bl = WL[(s * 8 + t) * 64 + lane];
            acc[t] = __builtin_amdgcn_mfma_f32_16x16x32_bf16(ah, bh, acc[t], 0, 0, 0);
            acc[t] = __builtin_amdgcn_mfma_f32_16x16x32_bf16(ah, bl, acc[t], 0, 0, 0);
            acc[t] = __builtin_amdgcn_mfma_f32_16x16x32_bf16(al, bh, acc[t], 0, 0, 0);
        }
    }

    // epilogue: bias -> row sum-of-squares -> normalize -> relu -> store
    float ssq[4] = {0.f, 0.f, 0.f, 0.f};
#pragma unroll
    for (int t = 0; t < 8; ++t) {
        float bv = bias[t * 16 + n16];
#pragma unroll
        for (int r = 0; r < 4; ++r) {
            acc[t][r] += bv;
            ssq[r] += acc[t][r] * acc[t][r];
        }
    }
#pragma unroll
    for (int mask = 1; mask <= 8; mask <<= 1) {
#pragma unroll
        for (int r = 0; r < 4; ++r) ssq[r] += __shfl_xor(ssq[r], mask);
    }
    float inv[4];
#pragma unroll
    for (int r = 0; r < 4; ++r) inv[r] = 1.0f / fmaxf(sqrtf(ssq[r]), 1e-12f);

    int orow0 = base + wave * 16 + quad * 4;
#pragma unroll
    for (int r = 0; r < 4; ++r) {
        int orow = orow0 + r;
        if (orow < M) {
            float* op = out + (size_t)orow * NFEAT + n16;
#pragma unroll
            for (int t = 0; t < 8; ++t) op[t * 16] = fmaxf(acc[t][r] * inv[r], 0.f);
        }
    }
}

// ---------------- classifier: logits = x4 @ Wl + bl; softmax (R2 proven) ----------------

__global__ __launch_bounds__(256) void classifier_kernel(const float* __restrict__ x4,
                                                         const float* __restrict__ Wl,
                                                         const float* __restrict__ bl,
                                                         float* __restrict__ logits,
                                                         float* __restrict__ probs, int n_nodes) {
    int node = blockIdx.x * 256 + threadIdx.x;
    int nc = node < n_nodes ? node : n_nodes - 1;
    const float* row = x4 + (size_t)nc * NFEAT;

    float acc[NCLASS];
#pragma unroll
    for (int c = 0; c < NCLASS; ++c) acc[c] = bl[c];

    for (int k = 0; k < NFEAT; k += 4) {
        float4 a = *(const float4*)(row + k);
#pragma unroll
        for (int kk = 0; kk < 4; ++kk) {
            float av = (&a.x)[kk];
            const float* Wr = Wl + (k + kk) * NCLASS;
#pragma unroll
            for (int c = 0; c < NCLASS; ++c) acc[c] += av * Wr[c];
        }
    }

    float m = acc[0];
#pragma unroll
    for (int c = 1; c < NCLASS; ++c) m = fmaxf(m, acc[c]);
    float ex[NCLASS];
    float sum = 0.f;
#pragma unroll
    for (int c = 0; c < NCLASS; ++c) {
        ex[c] = __expf(acc[c] - m);
        sum += ex[c];
    }
    float is = 1.0f / sum;

    if (node < n_nodes) {
        float4* lo = (float4*)(logits + (size_t)node * NCLASS);
        float4* po = (float4*)(probs + (size_t)node * NCLASS);
#pragma unroll
        for (int c = 0; c < NCLASS; c += 4) {
            float4 lv, pv;
            lv.x = acc[c + 0]; lv.y = acc[c + 1]; lv.z = acc[c + 2]; lv.w = acc[c + 3];
            pv.x = ex[c + 0] * is; pv.y = ex[c + 1] * is; pv.z = ex[c + 2] * is; pv.w = ex[c + 3] * is;
            lo[c >> 2] = lv;
            po[c >> 2] = pv;
        }
    }
}

// ---------------- launch ----------------

extern "C" void kernel_launch(void* const* d_in, const int* in_sizes, int n_in,
                              void* d_out, int out_size, void* d_ws, size_t ws_size,
                              hipStream_t stream) {
    const float* x  = (const float*)d_in[0];
    const int*   ei = (const int*)d_in[1];
    const float* W1 = (const float*)d_in[2];
    const float* b1 = (const float*)d_in[3];
    const float* W2 = (const float*)d_in[4];
    const float* b2 = (const float*)d_in[5];
    const float* W3 = (const float*)d_in[6];
    const float* b3 = (const float*)d_in[7];
    const float* W4 = (const float*)d_in[8];
    const float* b4 = (const float*)d_in[9];
    const float* Wl = (const float*)d_in[10];
    const float* bl = (const float*)d_in[11];

    const int n_nodes = in_sizes[0] / NFEAT;  // 50000
    const int n_edges = in_sizes[1] / 2;      // 640000
    const int* src = ei;
    const int* dst = ei + n_edges;

    float* out    = (float*)d_out;
    float* logits = out;
    float* probs  = out + (size_t)n_nodes * NCLASS;
    float* x4     = out + 2 * (size_t)n_nodes * NCLASS;  // layer ping buffer

    // workspace layout
    char* ws = (char*)d_ws;
    size_t off = 0;
    auto wsalloc = [&](size_t bytes) -> void* {
        void* p = ws + off;
        off += (bytes + 255) & ~(size_t)255;
        return p;
    };
    float* agg        = (float*)wsalloc((size_t)n_nodes * NFEAT * sizeof(float));
    float* xbuf       = (float*)wsalloc((size_t)n_nodes * NFEAT * sizeof(float));  // layer pong
    int*   row_ptr    = (int*)wsalloc(((size_t)n_nodes + 1) * sizeof(int));
    int*   woff       = (int*)wsalloc((size_t)n_nodes * sizeof(int));
    int*   cnt        = (int*)wsalloc((size_t)n_nodes * sizeof(int));
    int*   src_sorted = (int*)wsalloc((size_t)n_edges * sizeof(int));
    int    nb         = (n_nodes + 255) / 256;
    int*   bsums      = (int*)wsalloc(((size_t)nb + 1) * sizeof(int));
    short* whi        = (short*)wsalloc((size_t)4 * 16384 * sizeof(short));
    short* wlo        = (short*)wsalloc((size_t)4 * 16384 * sizeof(short));

    hipMemsetAsync(cnt, 0, (size_t)n_nodes * sizeof(int), stream);

    // W fragment prep (all 4 layers, one launch)
    wprep_kernel<<<dim3(8, 4), 256, 0, stream>>>(W1, W2, W3, W4, whi, wlo);

    // CSR build (dst-bucketed)
    int eb = (n_edges + 255) / 256;
    hist_kernel<<<eb, 256, 0, stream>>>(dst, cnt, n_edges);
    scan1_kernel<<<nb, 256, 0, stream>>>(cnt, row_ptr /*excl temp*/, bsums, n_nodes);
    scan2_kernel<<<1, 256, 0, stream>>>(bsums, nb);
    scan3_kernel<<<nb, 256, 0, stream>>>(row_ptr, bsums, row_ptr, woff, n_nodes, nb);
    scatter_kernel<<<eb, 256, 0, stream>>>(src, dst, woff, src_sorted, n_edges);

    int ab = (n_nodes + 7) / 8;
    int gb = (n_nodes + 63) / 64;
    int cb = (n_nodes + 255) / 256;

    // fused layers (agg-first reordering: segment_sum commutes with @W)
    agg_kernel<<<ab, 256, 0, stream>>>(x, row_ptr, src_sorted, agg, n_nodes);
    gemm_mfma_kernel<<<gb, 256, 0, stream>>>(agg, whi + 0 * 16384, wlo + 0 * 16384, b1, xbuf, n_nodes);
    agg_kernel<<<ab, 256, 0, stream>>>(xbuf, row_ptr, src_sorted, agg, n_nodes);
    gemm_mfma_kernel<<<gb, 256, 0, stream>>>(agg, whi + 1 * 16384, wlo + 1 * 16384, b2, x4, n_nodes);
    agg_kernel<<<ab, 256, 0, stream>>>(x4, row_ptr, src_sorted, agg, n_nodes);
    gemm_mfma_kernel<<<gb, 256, 0, stream>>>(agg, whi + 2 * 16384, wlo + 2 * 16384, b3, xbuf, n_nodes);
    agg_kernel<<<ab, 256, 0, stream>>>(xbuf, row_ptr, src_sorted, agg, n_nodes);
    gemm_mfma_kernel<<<gb, 256, 0, stream>>>(agg, whi + 3 * 16384, wlo + 3 * 16384, b4, x4, n_nodes);

    // classifier + softmax
    classifier_kernel<<<cb, 256, 0, stream>>>(x4, Wl, bl, logits, probs, n_nodes);
}

// Round 7
// 380.841 us; speedup vs baseline: 3.1675x; 1.1910x over previous
//
#include <hip/hip_runtime.h>
#include <hip/hip_bf16.h>
#include <hip/hip_fp16.h>
#include <math.h>

#define NFEAT 128
#define NCLASS 40

typedef __attribute__((ext_vector_type(8))) short frag_ab;   // 8 bf16 (4 VGPRs)
typedef __attribute__((ext_vector_type(4))) float frag_cd;   // 4 fp32 acc

static __device__ inline unsigned short f2bf_rne(float f) {
    union { float f; unsigned u; } v;
    v.f = f;
    unsigned r = v.u + 0x7FFFu + ((v.u >> 16) & 1u);  // round-to-nearest-even
    return (unsigned short)(r >> 16);
}
static __device__ inline float bf2f(unsigned short h) {
    union { unsigned u; float f; } v;
    v.u = ((unsigned)h) << 16;
    return v.f;
}

// ---------------- CSR build ----------------

__global__ __launch_bounds__(256) void hist_kernel(const int* __restrict__ dst,
                                                   int* __restrict__ counts, int n_edges) {
    int i = blockIdx.x * 256 + threadIdx.x;
    int n4 = n_edges >> 2;
    if (i < n4) {
        int4 d = ((const int4*)dst)[i];
        atomicAdd(&counts[d.x], 1);  // independent, fire-and-forget: pipeline
        atomicAdd(&counts[d.y], 1);
        atomicAdd(&counts[d.z], 1);
        atomicAdd(&counts[d.w], 1);
    }
    if (i == 0) {
        for (int e = n4 << 2; e < n_edges; ++e) atomicAdd(&counts[dst[e]], 1);
    }
}

__global__ __launch_bounds__(256) void scan1_kernel(const int* __restrict__ cnt,
                                                    int* __restrict__ excl,
                                                    int* __restrict__ bsums, int n) {
    __shared__ int sd[256];
    int t = threadIdx.x;
    int i = blockIdx.x * 256 + t;
    int v = (i < n) ? cnt[i] : 0;
    sd[t] = v;
    __syncthreads();
#pragma unroll
    for (int off = 1; off < 256; off <<= 1) {
        int tmp = (t >= off) ? sd[t - off] : 0;
        __syncthreads();
        sd[t] += tmp;
        __syncthreads();
    }
    if (i < n) excl[i] = sd[t] - v;
    if (t == 255) bsums[blockIdx.x] = sd[255];
}

__global__ __launch_bounds__(256) void scan2_kernel(int* __restrict__ bsums, int nb) {
    __shared__ int sd[256];
    int t = threadIdx.x;
    int v = (t < nb) ? bsums[t] : 0;
    sd[t] = v;
    __syncthreads();
#pragma unroll
    for (int off = 1; off < 256; off <<= 1) {
        int tmp = (t >= off) ? sd[t - off] : 0;
        __syncthreads();
        sd[t] += tmp;
        __syncthreads();
    }
    if (t < nb) bsums[t] = sd[t] - v;
    if (t == 255) bsums[nb] = sd[255];
}

__global__ __launch_bounds__(256) void scan3_kernel(const int* __restrict__ excl,
                                                    const int* __restrict__ bsums,
                                                    int* __restrict__ row_ptr,
                                                    int* __restrict__ woff, int n, int nb) {
    int i = blockIdx.x * 256 + threadIdx.x;
    if (i < n) {
        int v = excl[i] + bsums[blockIdx.x];
        row_ptr[i] = v;
        woff[i] = v;
    }
    if (i == 0) row_ptr[n] = bsums[nb];
}

__global__ __launch_bounds__(256) void scatter_kernel(const int* __restrict__ src,
                                                      const int* __restrict__ dst,
                                                      int* __restrict__ woff,
                                                      int* __restrict__ src_sorted, int n_edges) {
    int i = blockIdx.x * 256 + threadIdx.x;
    int n4 = n_edges >> 2;
    if (i < n4) {
        int4 d = ((const int4*)dst)[i];
        int4 s = ((const int4*)src)[i];
        int p0 = atomicAdd(&woff[d.x], 1);
        int p1 = atomicAdd(&woff[d.y], 1);
        int p2 = atomicAdd(&woff[d.z], 1);
        int p3 = atomicAdd(&woff[d.w], 1);
        src_sorted[p0] = s.x;
        src_sorted[p1] = s.y;
        src_sorted[p2] = s.z;
        src_sorted[p3] = s.w;
    }
    if (i == 0) {
        for (int e = n4 << 2; e < n_edges; ++e) {
            int p = atomicAdd(&woff[dst[e]], 1);
            src_sorted[p] = src[e];
        }
    }
}

// ---------------- fp32 -> fp16 convert (x only, once per call) ----------------

__global__ __launch_bounds__(256) void conv_h_kernel(const float* __restrict__ in,
                                                     __half* __restrict__ out, int n4) {
    int i = blockIdx.x * 256 + threadIdx.x;
    if (i < n4) {
        float4 v = ((const float4*)in)[i];
        __half2 h0 = __floats2half2_rn(v.x, v.y);
        __half2 h1 = __floats2half2_rn(v.z, v.w);
        ((__half2*)out)[i * 2 + 0] = h0;
        ((__half2*)out)[i * 2 + 1] = h1;
    }
}

// ---------------- aggregation over fp16 features ----------------
// Quarter-wave (16 lanes x 16 B = full 256 B fp16 row) per node; 4-deep gather
// pipeline -> 2x edges in flight vs the fp32 shape at half the bytes.
// Accumulate fp32, write fp32 agg (keeps gemm's split-bf16 path exact).

__global__ __launch_bounds__(256) void agg_h_kernel(const __half* __restrict__ xin,
                                                    const int* __restrict__ row_ptr,
                                                    const int* __restrict__ src_sorted,
                                                    float* __restrict__ agg, int n_nodes) {
    int node = blockIdx.x * 16 + (threadIdx.x >> 4);
    if (node >= n_nodes) return;
    int c = threadIdx.x & 15;  // 16B group: cols [8c, 8c+8)
    int jb = row_ptr[node], je = row_ptr[node + 1];
    const uint4* xp = (const uint4*)xin;  // fp16 row = 16 uint4

    float a[8];
#pragma unroll
    for (int i = 0; i < 8; ++i) a[i] = 0.f;

    int j = jb;
    for (; j + 3 < je; j += 4) {
        int s0 = src_sorted[j];
        int s1 = src_sorted[j + 1];
        int s2 = src_sorted[j + 2];
        int s3 = src_sorted[j + 3];
        uint4 r0 = xp[s0 * 16 + c];
        uint4 r1 = xp[s1 * 16 + c];
        uint4 r2 = xp[s2 * 16 + c];
        uint4 r3 = xp[s3 * 16 + c];
#pragma unroll
        for (int q = 0; q < 4; ++q) {
            unsigned u0 = (&r0.x)[q], u1 = (&r1.x)[q], u2 = (&r2.x)[q], u3 = (&r3.x)[q];
            float2 f0 = __half22float2(*(__half2*)&u0);
            float2 f1 = __half22float2(*(__half2*)&u1);
            float2 f2 = __half22float2(*(__half2*)&u2);
            float2 f3 = __half22float2(*(__half2*)&u3);
            a[q * 2 + 0] += f0.x + f1.x + f2.x + f3.x;
            a[q * 2 + 1] += f0.y + f1.y + f2.y + f3.y;
        }
    }
    for (; j < je; ++j) {
        int s0 = src_sorted[j];
        uint4 r0 = xp[s0 * 16 + c];
#pragma unroll
        for (int q = 0; q < 4; ++q) {
            unsigned u0 = (&r0.x)[q];
            float2 f0 = __half22float2(*(__half2*)&u0);
            a[q * 2 + 0] += f0.x;
            a[q * 2 + 1] += f0.y;
        }
    }
    float4* op = (float4*)agg + (size_t)node * 32 + c * 2;
    op[0] = make_float4(a[0], a[1], a[2], a[3]);
    op[1] = make_float4(a[4], a[5], a[6], a[7]);
}

// ---------------- W fragment prep (unchanged, verified) ----------------

__global__ __launch_bounds__(256) void wprep_kernel(const float* __restrict__ W0,
                                                    const float* __restrict__ W1,
                                                    const float* __restrict__ W2,
                                                    const float* __restrict__ W3,
                                                    short* __restrict__ whi,
                                                    short* __restrict__ wlo) {
    int layer = blockIdx.y;
    const float* W = layer == 0 ? W0 : layer == 1 ? W1 : layer == 2 ? W2 : W3;
    short* h = whi + (size_t)layer * 16384;
    short* l = wlo + (size_t)layer * 16384;
    int idx = blockIdx.x * 256 + threadIdx.x;  // 0..2047 frag slots
    int lane = idx & 63;
    int t = (idx >> 6) & 7;
    int s = idx >> 9;
    int quad = lane >> 4;
    int n = lane & 15;
    int kbase = s * 32 + quad * 8;
    int col = t * 16 + n;
#pragma unroll
    for (int j = 0; j < 8; ++j) {
        float f = W[(size_t)(kbase + j) * NFEAT + col];
        unsigned short hb = f2bf_rne(f);
        unsigned short lb = f2bf_rne(f - bf2f(hb));
        h[(size_t)idx * 8 + j] = (short)hb;
        l[(size_t)idx * 8 + j] = (short)lb;
    }
}

// ---------------- MFMA GEMM + bias + L2-normalize + ReLU ----------------
// Split-bf16 (hi*hi + hi*lo + lo*hi), fp32 acc — verified in R5 (absmax 9.8e-4).
// Output: fp16 (layers 1-3, outh) or fp32 (layer 4, outf).

__global__ __launch_bounds__(256) void gemm_mfma_kernel(const float* __restrict__ A,
                                                        const short* __restrict__ whi,
                                                        const short* __restrict__ wlo,
                                                        const float* __restrict__ bias,
                                                        float* __restrict__ outf,
                                                        __half* __restrict__ outh, int M) {
    int tid = threadIdx.x;
    int wave = tid >> 6;
    int lane = tid & 63;
    int quad = lane >> 4;
    int n16 = lane & 15;
    int base = blockIdx.x * 64;

    int arow = base + wave * 16 + n16;
    int arc = arow < M ? arow : M - 1;
    const float* Ar = A + (size_t)arc * NFEAT;

    const frag_ab* WH = (const frag_ab*)whi;
    const frag_ab* WL = (const frag_ab*)wlo;

    frag_cd acc[8];
#pragma unroll
    for (int t = 0; t < 8; ++t) acc[t] = (frag_cd){0.f, 0.f, 0.f, 0.f};

#pragma unroll
    for (int s = 0; s < 4; ++s) {
        const float* ap = Ar + s * 32 + quad * 8;
        float4 x0 = *(const float4*)ap;
        float4 x1 = *(const float4*)(ap + 4);
        float xs[8] = {x0.x, x0.y, x0.z, x0.w, x1.x, x1.y, x1.z, x1.w};
        frag_ab ah, al;
#pragma unroll
        for (int j = 0; j < 8; ++j) {
            unsigned short hb = f2bf_rne(xs[j]);
            ah[j] = (short)hb;
            al[j] = (short)f2bf_rne(xs[j] - bf2f(hb));
        }
#pragma unroll
        for (int t = 0; t < 8; ++t) {
            frag_ab bh = WH[(s * 8 + t) * 64 + lane];
            frag_ab bl = WL[(s * 8 + t) * 64 + lane];
            acc[t] = __builtin_amdgcn_mfma_f32_16x16x32_bf16(ah, bh, acc[t], 0, 0, 0);
            acc[t] = __builtin_amdgcn_mfma_f32_16x16x32_bf16(ah, bl, acc[t], 0, 0, 0);
            acc[t] = __builtin_amdgcn_mfma_f32_16x16x32_bf16(al, bh, acc[t], 0, 0, 0);
        }
    }

    // epilogue: bias -> row sum-of-squares -> normalize -> relu -> store
    float ssq[4] = {0.f, 0.f, 0.f, 0.f};
#pragma unroll
    for (int t = 0; t < 8; ++t) {
        float bv = bias[t * 16 + n16];
#pragma unroll
        for (int r = 0; r < 4; ++r) {
            acc[t][r] += bv;
            ssq[r] += acc[t][r] * acc[t][r];
        }
    }
#pragma unroll
    for (int mask = 1; mask <= 8; mask <<= 1) {
#pragma unroll
        for (int r = 0; r < 4; ++r) ssq[r] += __shfl_xor(ssq[r], mask);
    }
    float inv[4];
#pragma unroll
    for (int r = 0; r < 4; ++r) inv[r] = 1.0f / fmaxf(sqrtf(ssq[r]), 1e-12f);

    int orow0 = base + wave * 16 + quad * 4;
#pragma unroll
    for (int r = 0; r < 4; ++r) {
        int orow = orow0 + r;
        if (orow < M) {
            if (outh) {
                __half* op = outh + (size_t)orow * NFEAT + n16;
#pragma unroll
                for (int t = 0; t < 8; ++t)
                    op[t * 16] = __float2half(fmaxf(acc[t][r] * inv[r], 0.f));
            } else {
                float* op = outf + (size_t)orow * NFEAT + n16;
#pragma unroll
                for (int t = 0; t < 8; ++t)
                    op[t * 16] = fmaxf(acc[t][r] * inv[r], 0.f);
            }
        }
    }
}

// ---------------- classifier: logits = x4 @ Wl + bl; softmax (R2 proven) ----------------

__global__ __launch_bounds__(256) void classifier_kernel(const float* __restrict__ x4,
                                                         const float* __restrict__ Wl,
                                                         const float* __restrict__ bl,
                                                         float* __restrict__ logits,
                                                         float* __restrict__ probs, int n_nodes) {
    int node = blockIdx.x * 256 + threadIdx.x;
    int nc = node < n_nodes ? node : n_nodes - 1;
    const float* row = x4 + (size_t)nc * NFEAT;

    float acc[NCLASS];
#pragma unroll
    for (int c = 0; c < NCLASS; ++c) acc[c] = bl[c];

    for (int k = 0; k < NFEAT; k += 4) {
        float4 a = *(const float4*)(row + k);
#pragma unroll
        for (int kk = 0; kk < 4; ++kk) {
            float av = (&a.x)[kk];
            const float* Wr = Wl + (k + kk) * NCLASS;
#pragma unroll
            for (int c = 0; c < NCLASS; ++c) acc[c] += av * Wr[c];
        }
    }

    float m = acc[0];
#pragma unroll
    for (int c = 1; c < NCLASS; ++c) m = fmaxf(m, acc[c]);
    float ex[NCLASS];
    float sum = 0.f;
#pragma unroll
    for (int c = 0; c < NCLASS; ++c) {
        ex[c] = __expf(acc[c] - m);
        sum += ex[c];
    }
    float is = 1.0f / sum;

    if (node < n_nodes) {
        float4* lo = (float4*)(logits + (size_t)node * NCLASS);
        float4* po = (float4*)(probs + (size_t)node * NCLASS);
#pragma unroll
        for (int c = 0; c < NCLASS; c += 4) {
            float4 lv, pv;
            lv.x = acc[c + 0]; lv.y = acc[c + 1]; lv.z = acc[c + 2]; lv.w = acc[c + 3];
            pv.x = ex[c + 0] * is; pv.y = ex[c + 1] * is; pv.z = ex[c + 2] * is; pv.w = ex[c + 3] * is;
            lo[c >> 2] = lv;
            po[c >> 2] = pv;
        }
    }
}

// ---------------- launch ----------------

extern "C" void kernel_launch(void* const* d_in, const int* in_sizes, int n_in,
                              void* d_out, int out_size, void* d_ws, size_t ws_size,
                              hipStream_t stream) {
    const float* x  = (const float*)d_in[0];
    const int*   ei = (const int*)d_in[1];
    const float* W1 = (const float*)d_in[2];
    const float* b1 = (const float*)d_in[3];
    const float* W2 = (const float*)d_in[4];
    const float* b2 = (const float*)d_in[5];
    const float* W3 = (const float*)d_in[6];
    const float* b3 = (const float*)d_in[7];
    const float* W4 = (const float*)d_in[8];
    const float* b4 = (const float*)d_in[9];
    const float* Wl = (const float*)d_in[10];
    const float* bl = (const float*)d_in[11];

    const int n_nodes = in_sizes[0] / NFEAT;  // 50000
    const int n_edges = in_sizes[1] / 2;      // 640000
    const int* src = ei;
    const int* dst = ei + n_edges;

    float* out    = (float*)d_out;
    float* logits = out;
    float* probs  = out + (size_t)n_nodes * NCLASS;
    float* x4     = out + 2 * (size_t)n_nodes * NCLASS;  // final fp32 features

    // workspace layout
    char* ws = (char*)d_ws;
    size_t off = 0;
    auto wsalloc = [&](size_t bytes) -> void* {
        void* p = ws + off;
        off += (bytes + 255) & ~(size_t)255;
        return p;
    };
    float*  agg        = (float*)wsalloc((size_t)n_nodes * NFEAT * sizeof(float));
    __half* xh         = (__half*)wsalloc((size_t)n_nodes * NFEAT * sizeof(__half));  // fp16 feature buf
    int*    row_ptr    = (int*)wsalloc(((size_t)n_nodes + 1) * sizeof(int));
    int*    woff       = (int*)wsalloc((size_t)n_nodes * sizeof(int));
    int*    cnt        = (int*)wsalloc((size_t)n_nodes * sizeof(int));
    int*    src_sorted = (int*)wsalloc((size_t)n_edges * sizeof(int));
    int     nb         = (n_nodes + 255) / 256;
    int*    bsums      = (int*)wsalloc(((size_t)nb + 1) * sizeof(int));
    short*  whi        = (short*)wsalloc((size_t)4 * 16384 * sizeof(short));
    short*  wlo        = (short*)wsalloc((size_t)4 * 16384 * sizeof(short));

    hipMemsetAsync(cnt, 0, (size_t)n_nodes * sizeof(int), stream);

    // W fragment prep (all 4 layers, one launch)
    wprep_kernel<<<dim3(8, 4), 256, 0, stream>>>(W1, W2, W3, W4, whi, wlo);

    // x -> fp16
    int xc4 = (n_nodes * NFEAT) / 4;
    conv_h_kernel<<<(xc4 + 255) / 256, 256, 0, stream>>>(x, xh, xc4);

    // CSR build (dst-bucketed)
    int e4b = ((n_edges >> 2) + 255) / 256;
    hist_kernel<<<e4b, 256, 0, stream>>>(dst, cnt, n_edges);
    scan1_kernel<<<nb, 256, 0, stream>>>(cnt, row_ptr /*excl temp*/, bsums, n_nodes);
    scan2_kernel<<<1, 256, 0, stream>>>(bsums, nb);
    scan3_kernel<<<nb, 256, 0, stream>>>(row_ptr, bsums, row_ptr, woff, n_nodes, nb);
    scatter_kernel<<<e4b, 256, 0, stream>>>(src, dst, woff, src_sorted, n_edges);

    int ah = (n_nodes + 15) / 16;
    int gb = (n_nodes + 63) / 64;
    int cb = (n_nodes + 255) / 256;

    // fused layers (agg-first reordering; single fp16 buffer — serial stream,
    // each producer fully consumed before overwrite)
    agg_h_kernel<<<ah, 256, 0, stream>>>(xh, row_ptr, src_sorted, agg, n_nodes);
    gemm_mfma_kernel<<<gb, 256, 0, stream>>>(agg, whi + 0 * 16384, wlo + 0 * 16384, b1, nullptr, xh, n_nodes);
    agg_h_kernel<<<ah, 256, 0, stream>>>(xh, row_ptr, src_sorted, agg, n_nodes);
    gemm_mfma_kernel<<<gb, 256, 0, stream>>>(agg, whi + 1 * 16384, wlo + 1 * 16384, b2, nullptr, xh, n_nodes);
    agg_h_kernel<<<ah, 256, 0, stream>>>(xh, row_ptr, src_sorted, agg, n_nodes);
    gemm_mfma_kernel<<<gb, 256, 0, stream>>>(agg, whi + 2 * 16384, wlo + 2 * 16384, b3, nullptr, xh, n_nodes);
    agg_h_kernel<<<ah, 256, 0, stream>>>(xh, row_ptr, src_sorted, agg, n_nodes);
    gemm_mfma_kernel<<<gb, 256, 0, stream>>>(agg, whi + 3 * 16384, wlo + 3 * 16384, b4, x4, nullptr, n_nodes);

    // classifier + softmax
    classifier_kernel<<<cb, 256, 0, stream>>>(x4, Wl, bl, logits, probs, n_nodes);
}